// Round 12
// baseline (376.307 us; speedup 1.0000x reference)
//
#include <hip/hip_runtime.h>

// y[n,m,:] = x[n,m,:] @ W[l(m)] * (1/sqrt(128))
// x: [100000, 16, 128] f32   W: [4, 128, 128] f32   y: [100000, 16, 128] f32
//
// R11 post-mortem: barrier-free wave-private pipeline regressed (373us) ->
// barriers were never the residual; 4x L2 amplification cost more. Reverted
// to R10 (305us best). Remaining hard evidence: FETCH_SIZE ~404MB = only
// half of x comes from HBM (L3 serves the rest across graph replays), so L3
// residency is first-order -- and y's 800MB zero-reuse write stream is
// polluting it. R12 (single variable vs R10): NON-TEMPORAL stores for y
// (gfx950 nt flag) so y bypasses L2/L3 allocation -> more of x stays
// resident -> less HBM fetch.
//
// Base structure (R10): 512-thr blocks over an m-PAIR (waves 0-3 m0, 4-7
// m1, each a 32-wide d-slice; weights 32 VGPR/wave). Tile = 32 rows x 2m =
// 32KB; every stage instruction = one wave reading one contiguous 1KB
// row-chunk. Two buffers = 64KB LDS -> 2 blocks/CU. 2-phase schedule,
// steady vmcnt(4). Rule #21 both-sides swizzle: source slot = lane^(r&7),
// linear DMA dest, XOR on ds_read (2-way bank = free). m-pairs-fast grid
// (R6 page-locality win). MFMA: A=W-frag(d), B=x-frag(n), same
// k->(lanegroup,elem) map both sides (K-perm cancels). D: col(lane&15)=n,
// row((lane>>4)*4+reg)=d (HW-verified R1-R11).

typedef __bf16 bf16x8 __attribute__((ext_vector_type(8)));
typedef float f32x4 __attribute__((ext_vector_type(4)));
typedef unsigned short u16x8 __attribute__((ext_vector_type(8)));

#define N_NODES 100000
#define MCOMP 16
#define CIN 128
#define ROWSTRIDE (MCOMP * CIN)  // 2048 floats per node
#define TROWS 32                 // rows per tile (x 2 m = 32 KB)
#define TPB 4                    // tiles per block (128 rows)

__device__ __forceinline__ unsigned short f2b(float f) {
    unsigned int u = __float_as_uint(f);
    unsigned int r = (u + 0x7fffu + ((u >> 16) & 1u)) >> 16;
    return (unsigned short)r;
}

// Wt[l][d][c] = W[l][c][d] * (1/sqrt(128)) as bf16 bits. 128 KiB in d_ws.
__global__ void prep_weights(const float* __restrict__ w,
                             unsigned short* __restrict__ wt) {
    int idx = blockIdx.x * blockDim.x + threadIdx.x;  // 0..65535
    int l = idx >> 14;
    int rem = idx & 16383;
    int d = rem >> 7;
    int c = rem & 127;
    const float pw = 0.08838834764831845f;  // 1/sqrt(128)
    wt[idx] = f2b(w[(l << 14) + (c << 7) + d] * pw);
}

__global__ __launch_bounds__(512, 4) void linear_mfma(
        const float* __restrict__ x,
        const unsigned short* __restrict__ wt,
        float* __restrict__ y) {
    __shared__ float lds0[TROWS * 256];  // 32 KiB: 32 rows x (2m x 128c)
    __shared__ float lds1[TROWS * 256];

    const int m0 = blockIdx.x * 2;      // m-pair, FAST dispatch dim
    const int wid = threadIdx.x >> 6;   // 0..7
    const int mu = wid >> 2;            // 0: m0, 1: m0+1
    const int wq = wid & 3;             // d-slice [wq*32, +32) within its m
    const int lane = threadIdx.x & 63;
    const int lr = lane & 15;   // W-frag d-row / x-frag n(row) / D col
    const int lk = lane >> 4;   // k lane-group
    const int nbase = blockIdx.y * (TROWS * TPB);  // 128 rows per block

    const int m = m0 + mu;
    const int l = (m >= 9) ? 3 : (m >= 4) ? 2 : (m >= 1) ? 1 : 0;

    // W fragments, register-resident (32 VGPR):
    // d = wq*32 + df*16 + lr, k = kk*32 + lk*8 .. +8
    const unsigned short* wl = wt + (l << 14);
    bf16x8 wf[2][4];
#pragma unroll
    for (int df = 0; df < 2; ++df)
#pragma unroll
        for (int kk = 0; kk < 4; ++kk)
            wf[df][kk] = __builtin_bit_cast(bf16x8, *(const u16x8*)(
                wl + (((wq * 32 + df * 16 + lr) << 7) + kk * 32 + lk * 8)));

    // stage tile t: 32 rows x 1KB (both m). 4 instrs/wave; each instruction
    // = one wave reading one CONTIGUOUS 1KB row-chunk. Source slot pre-
    // swizzled lane^(r&7) (within-half XOR), LDS dest linear.
    auto stage = [&](float* buf, int t) {
        const int hbase = nbase + t * TROWS;
#pragma unroll
        for (int j = 0; j < 4; ++j) {
            int r = wid * 4 + j;                 // row 0..31, wave-uniform
            int slot = lane ^ (r & 7);           // 16B slot within 1KB row
            const float* src = x + (size_t)(hbase + r) * ROWSTRIDE
                               + m0 * CIN + slot * 4;
            __builtin_amdgcn_global_load_lds(
                (const __attribute__((address_space(1))) void*)src,
                (__attribute__((address_space(3))) void*)(buf + r * 256),
                16, 0, 0);
        }
    };

    // compute tile t: per wave 8 ds_read_b128 (deswizzled), 16 MFMA,
    // 4 NON-TEMPORAL dwordx4 stores (y has zero reuse -- keep it out of
    // L2/L3 so x stays resident).
    auto comp = [&](const float* buf, int t) {
        f32x4 acc[2][2];
#pragma unroll
        for (int rf = 0; rf < 2; ++rf)
#pragma unroll
            for (int df = 0; df < 2; ++df)
                acc[rf][df] = (f32x4){0.f, 0.f, 0.f, 0.f};

#pragma unroll
        for (int kk = 0; kk < 4; ++kk)
#pragma unroll
            for (int rf = 0; rf < 2; ++rf) {
                int row = rf * 16 + lr;
                int sw = row & 7;
                const float* rbase = buf + row * 256 + mu * 128 + kk * 32;
                f32x4 v0 = *(const f32x4*)(rbase + ((lk * 2) ^ sw) * 4);
                f32x4 v1 = *(const f32x4*)(rbase + ((lk * 2 + 1) ^ sw) * 4);
                bf16x8 xb;
#pragma unroll
                for (int jj = 0; jj < 4; ++jj) {
                    xb[jj] = (__bf16)v0[jj];
                    xb[jj + 4] = (__bf16)v1[jj];
                }
                acc[rf][0] = __builtin_amdgcn_mfma_f32_16x16x32_bf16(
                    wf[0][kk], xb, acc[rf][0], 0, 0, 0);
                acc[rf][1] = __builtin_amdgcn_mfma_f32_16x16x32_bf16(
                    wf[1][kk], xb, acc[rf][1], 0, 0, 0);
            }

        const int hbase = nbase + t * TROWS;
#pragma unroll
        for (int rf = 0; rf < 2; ++rf)
#pragma unroll
            for (int df = 0; df < 2; ++df) {
                float* yp = y + (size_t)(hbase + rf * 16 + lr) * ROWSTRIDE
                            + m * CIN + wq * 32 + df * 16 + lk * 4;
                __builtin_nontemporal_store(acc[rf][df], (f32x4*)yp);
            }
    };

    if (nbase + TROWS * TPB <= N_NODES) {
        // R6 schedule, 4 tiles: per wave 4 loads + 4 stores per iter.
        stage(lds0, 0);
        asm volatile("s_waitcnt vmcnt(0)" ::: "memory");
        __builtin_amdgcn_s_barrier();

        stage(lds1, 1);
        __builtin_amdgcn_sched_barrier(0);
        comp(lds0, 0);
        asm volatile("s_waitcnt vmcnt(4)" ::: "memory");  // L1 done, S0 out
        __builtin_amdgcn_s_barrier();

        stage(lds0, 2);
        __builtin_amdgcn_sched_barrier(0);
        comp(lds1, 1);
        asm volatile("s_waitcnt vmcnt(4)" ::: "memory");
        __builtin_amdgcn_s_barrier();

        stage(lds1, 3);
        __builtin_amdgcn_sched_barrier(0);
        comp(lds0, 2);
        asm volatile("s_waitcnt vmcnt(4)" ::: "memory");
        __builtin_amdgcn_s_barrier();

        comp(lds1, 3);
    } else {
        // tail block: 100000 % 128 == 32 -> exactly 1 tile
        stage(lds0, 0);
        asm volatile("s_waitcnt vmcnt(0)" ::: "memory");
        __builtin_amdgcn_s_barrier();
        comp(lds0, 0);
    }
}

extern "C" void kernel_launch(void* const* d_in, const int* in_sizes, int n_in,
                              void* d_out, int out_size, void* d_ws, size_t ws_size,
                              hipStream_t stream) {
    const float* x = (const float*)d_in[0];
    const float* w = (const float*)d_in[1];
    float* y = (float*)d_out;
    unsigned short* wt = (unsigned short*)d_ws;  // 128 KiB of scratch used

    prep_weights<<<256, 256, 0, stream>>>(w, wt);

    // m-pairs fast, node-tile slow: concurrent blocks cover all 16 m of
    // consecutive 128-row spans; every stage read is a contiguous 1KB chunk.
    dim3 grid(MCOMP / 2, (N_NODES + TROWS * TPB - 1) / (TROWS * TPB));  // 8x782
    linear_mfma<<<grid, 512, 0, stream>>>(x, wt, y);
}

// Round 13
// 304.377 us; speedup vs baseline: 1.2363x; 1.2363x over previous
//
#include <hip/hip_runtime.h>

// y[n,m,:] = x[n,m,:] @ W[l(m)] * (1/sqrt(128))
// x: [100000, 16, 128] f32   W: [4, 128, 128] f32   y: [100000, 16, 128] f32
//
// R12 post-mortem: nontemporal y-stores regressed (305->376us) -- bypassing
// L2/L3 allocation loses write-combining; reverted. FINAL FORM = R10
// (305us, best). Mechanism ledger over R4-R12: page-locality grid +11%
// (real); granularity +1%; depth, occupancy-down neutral; occupancy-up &
// m-pair-128cap confounded by register floor (~60-100 live VGPR needed);
// barrier-free -22%; nt stores -23%. Two unrelated structures (R6, R10)
// converge at 305-309us = external ceiling: 1.638 GB / 305us = 5.37 TB/s =
// 85% of the 6.29 TB/s mixed-copy ceiling, with inherent 16-way
// m-interleaved granule costs a pure copy doesn't pay. MFMA 4%, VALU 6%,
// LDS conflicts at 2-way b128 minimum, L2 far from ceiling -> memory-path
// bound. Expect ~305us; declare roofline on confirmation.
//
// Structure (R10): 512-thr blocks over an m-PAIR (waves 0-3 m0, 4-7 m1,
// each a 32-wide d-slice; weights 32 VGPR/wave, register-resident). Tile =
// 32 rows x 2m = 32KB; every stage instruction = one wave reading one
// contiguous 1KB row-chunk via global_load_lds(16B). Two buffers = 64KB LDS
// -> 2 blocks/CU. 2-phase schedule, counted vmcnt(4) + s_barrier,
// sched_barrier(0) phase pins. Rule #21 both-sides swizzle: source slot =
// lane^(r&7), linear DMA dest, XOR on ds_read (2-way bank = free).
// m-pairs-fast grid (R6 page-locality win). MFMA: A=W-frag(d), B=x-frag(n),
// same k->(lanegroup,elem) map both sides (K-perm cancels). D:
// col(lane&15)=n, row((lane>>4)*4+reg)=d (HW-verified R1-R12).

typedef __bf16 bf16x8 __attribute__((ext_vector_type(8)));
typedef float f32x4 __attribute__((ext_vector_type(4)));
typedef unsigned short u16x8 __attribute__((ext_vector_type(8)));

#define N_NODES 100000
#define MCOMP 16
#define CIN 128
#define ROWSTRIDE (MCOMP * CIN)  // 2048 floats per node
#define TROWS 32                 // rows per tile (x 2 m = 32 KB)
#define TPB 4                    // tiles per block (128 rows)

__device__ __forceinline__ unsigned short f2b(float f) {
    unsigned int u = __float_as_uint(f);
    unsigned int r = (u + 0x7fffu + ((u >> 16) & 1u)) >> 16;
    return (unsigned short)r;
}

// Wt[l][d][c] = W[l][c][d] * (1/sqrt(128)) as bf16 bits. 128 KiB in d_ws.
__global__ void prep_weights(const float* __restrict__ w,
                             unsigned short* __restrict__ wt) {
    int idx = blockIdx.x * blockDim.x + threadIdx.x;  // 0..65535
    int l = idx >> 14;
    int rem = idx & 16383;
    int d = rem >> 7;
    int c = rem & 127;
    const float pw = 0.08838834764831845f;  // 1/sqrt(128)
    wt[idx] = f2b(w[(l << 14) + (c << 7) + d] * pw);
}

__global__ __launch_bounds__(512, 4) void linear_mfma(
        const float* __restrict__ x,
        const unsigned short* __restrict__ wt,
        float* __restrict__ y) {
    __shared__ float lds0[TROWS * 256];  // 32 KiB: 32 rows x (2m x 128c)
    __shared__ float lds1[TROWS * 256];

    const int m0 = blockIdx.x * 2;      // m-pair, FAST dispatch dim
    const int wid = threadIdx.x >> 6;   // 0..7
    const int mu = wid >> 2;            // 0: m0, 1: m0+1
    const int wq = wid & 3;             // d-slice [wq*32, +32) within its m
    const int lane = threadIdx.x & 63;
    const int lr = lane & 15;   // W-frag d-row / x-frag n(row) / D col
    const int lk = lane >> 4;   // k lane-group
    const int nbase = blockIdx.y * (TROWS * TPB);  // 128 rows per block

    const int m = m0 + mu;
    const int l = (m >= 9) ? 3 : (m >= 4) ? 2 : (m >= 1) ? 1 : 0;

    // W fragments, register-resident (32 VGPR):
    // d = wq*32 + df*16 + lr, k = kk*32 + lk*8 .. +8
    const unsigned short* wl = wt + (l << 14);
    bf16x8 wf[2][4];
#pragma unroll
    for (int df = 0; df < 2; ++df)
#pragma unroll
        for (int kk = 0; kk < 4; ++kk)
            wf[df][kk] = __builtin_bit_cast(bf16x8, *(const u16x8*)(
                wl + (((wq * 32 + df * 16 + lr) << 7) + kk * 32 + lk * 8)));

    // stage tile t: 32 rows x 1KB (both m). 4 instrs/wave; each instruction
    // = one wave reading one CONTIGUOUS 1KB row-chunk. Source slot pre-
    // swizzled lane^(r&7) (within-half XOR), LDS dest linear.
    auto stage = [&](float* buf, int t) {
        const int hbase = nbase + t * TROWS;
#pragma unroll
        for (int j = 0; j < 4; ++j) {
            int r = wid * 4 + j;                 // row 0..31, wave-uniform
            int slot = lane ^ (r & 7);           // 16B slot within 1KB row
            const float* src = x + (size_t)(hbase + r) * ROWSTRIDE
                               + m0 * CIN + slot * 4;
            __builtin_amdgcn_global_load_lds(
                (const __attribute__((address_space(1))) void*)src,
                (__attribute__((address_space(3))) void*)(buf + r * 256),
                16, 0, 0);
        }
    };

    // compute tile t: per wave 8 ds_read_b128 (deswizzled), 16 MFMA, 4 stores.
    auto comp = [&](const float* buf, int t) {
        f32x4 acc[2][2];
#pragma unroll
        for (int rf = 0; rf < 2; ++rf)
#pragma unroll
            for (int df = 0; df < 2; ++df)
                acc[rf][df] = (f32x4){0.f, 0.f, 0.f, 0.f};

#pragma unroll
        for (int kk = 0; kk < 4; ++kk)
#pragma unroll
            for (int rf = 0; rf < 2; ++rf) {
                int row = rf * 16 + lr;
                int sw = row & 7;
                const float* rbase = buf + row * 256 + mu * 128 + kk * 32;
                f32x4 v0 = *(const f32x4*)(rbase + ((lk * 2) ^ sw) * 4);
                f32x4 v1 = *(const f32x4*)(rbase + ((lk * 2 + 1) ^ sw) * 4);
                bf16x8 xb;
#pragma unroll
                for (int jj = 0; jj < 4; ++jj) {
                    xb[jj] = (__bf16)v0[jj];
                    xb[jj + 4] = (__bf16)v1[jj];
                }
                acc[rf][0] = __builtin_amdgcn_mfma_f32_16x16x32_bf16(
                    wf[0][kk], xb, acc[rf][0], 0, 0, 0);
                acc[rf][1] = __builtin_amdgcn_mfma_f32_16x16x32_bf16(
                    wf[1][kk], xb, acc[rf][1], 0, 0, 0);
            }

        const int hbase = nbase + t * TROWS;
#pragma unroll
        for (int rf = 0; rf < 2; ++rf)
#pragma unroll
            for (int df = 0; df < 2; ++df) {
                float* yp = y + (size_t)(hbase + rf * 16 + lr) * ROWSTRIDE
                            + m * CIN + wq * 32 + df * 16 + lk * 4;
                *(f32x4*)yp = acc[rf][df];
            }
    };

    if (nbase + TROWS * TPB <= N_NODES) {
        // 2-phase schedule, 4 tiles: per wave 4 loads + 4 stores per iter.
        stage(lds0, 0);
        asm volatile("s_waitcnt vmcnt(0)" ::: "memory");
        __builtin_amdgcn_s_barrier();

        stage(lds1, 1);
        __builtin_amdgcn_sched_barrier(0);
        comp(lds0, 0);
        asm volatile("s_waitcnt vmcnt(4)" ::: "memory");  // L1 done, S0 out
        __builtin_amdgcn_s_barrier();

        stage(lds0, 2);
        __builtin_amdgcn_sched_barrier(0);
        comp(lds1, 1);
        asm volatile("s_waitcnt vmcnt(4)" ::: "memory");
        __builtin_amdgcn_s_barrier();

        stage(lds1, 3);
        __builtin_amdgcn_sched_barrier(0);
        comp(lds0, 2);
        asm volatile("s_waitcnt vmcnt(4)" ::: "memory");
        __builtin_amdgcn_s_barrier();

        comp(lds1, 3);
    } else {
        // tail block: 100000 % 128 == 32 -> exactly 1 tile
        stage(lds0, 0);
        asm volatile("s_waitcnt vmcnt(0)" ::: "memory");
        __builtin_amdgcn_s_barrier();
        comp(lds0, 0);
    }
}

extern "C" void kernel_launch(void* const* d_in, const int* in_sizes, int n_in,
                              void* d_out, int out_size, void* d_ws, size_t ws_size,
                              hipStream_t stream) {
    const float* x = (const float*)d_in[0];
    const float* w = (const float*)d_in[1];
    float* y = (float*)d_out;
    unsigned short* wt = (unsigned short*)d_ws;  // 128 KiB of scratch used

    prep_weights<<<256, 256, 0, stream>>>(w, wt);

    // m-pairs fast, node-tile slow: concurrent blocks cover all 16 m of
    // consecutive 128-row spans; every stage read is a contiguous 1KB chunk.
    dim3 grid(MCOMP / 2, (N_NODES + TROWS * TPB - 1) / (TROWS * TPB));  // 8x782
    linear_mfma<<<grid, 512, 0, stream>>>(x, wt, y);
}